// Round 1
// baseline (665.297 us; speedup 1.0000x reference)
//
#include <hip/hip_runtime.h>

// Spatial correlation (cost volume), B=8 C=128 H=W=96, patch 9x9, 3x3 box, pad 1.
// out[b,di,dj,y,x] = sum_{i,j in 0..2} P[b,di,dj,y+i,x+j]
// P[b,di,dj,y',x'] = sum_c q_pad[y',x'] * k_pad[y'+di, x'+dj]   (padded 98x98 grid)
// q_pad[y'] = q[y'-1] (zero OOB), k_pad[a] = k[a-5] (zero OOB).

#define BATCH 8
#define CHN   128
#define IMG   96
#define TILE  16    // P-tile edge (padded-grid points) per block
#define OTILE 14    // output-tile edge per block (TILE - 2)
#define NC    8     // channels staged per pass
#define NCB   (CHN / NC)
#define KT    24    // k-tile edge (TILE + 8)
#define KTP   28    // k-tile padded col stride (mult of 4, breaks pow2 banks)
#define QTP   20    // q-tile padded col stride
#define PTP   20    // box-sum tile padded col stride (allows unguarded 6-col reads)

struct Tiles {
  float qs[NC][TILE][QTP];   // 10240 B
  float ks[NC][KT][KTP];     // 21504 B
  float pt[4][TILE][PTP];    //  5120 B  (per-wave box-sum buffer)
};

__device__ inline void stage(const float* __restrict__ qg, const float* __restrict__ kg,
                             Tiles& t, int cb, int b, int X0, int Y0, int tid) {
  const int cbase = cb * NC;
  // q tile: NC*16*16 = 2048 elems, col-fastest => coalesced 64B row segments
  for (int idx = tid; idx < NC * TILE * TILE; idx += 256) {
    const int c = idx >> 8;
    const int rem = idx & 255;
    const int r = rem >> 4, col = rem & 15;
    const int gy = Y0 + r - 1, gx = X0 + col - 1;
    float v = 0.f;
    if ((unsigned)gy < IMG && (unsigned)gx < IMG)
      v = qg[((size_t)(b * CHN + cbase + c) * IMG + gy) * IMG + gx];
    t.qs[c][r][col] = v;
  }
  // k tile: NC*24*24 = 4608 elems
  for (int idx = tid; idx < NC * KT * KT; idx += 256) {
    const int c = idx / (KT * KT);
    const int rem = idx - c * (KT * KT);
    const int r = rem / KT, col = rem - r * KT;
    const int gy = Y0 + r - 5, gx = X0 + col - 5;
    float v = 0.f;
    if ((unsigned)gy < IMG && (unsigned)gx < IMG)
      v = kg[((size_t)(b * CHN + cbase + c) * IMG + gy) * IMG + gx];
    t.ks[c][r][col] = v;
  }
}

// One wave handles offsets o in [OB, OB+ON). di span of any 21-offset window is 3 rows.
template <int OB, int ON>
__device__ void run(const float* __restrict__ qg, const float* __restrict__ kg,
                    float* __restrict__ out, Tiles& t,
                    int b, int X0, int Y0, int tid, int w, int lane) {
  constexpr int DI0 = OB / 9;
  const int xg  = lane & 3;    // 4 x-groups of 4 points = 16 cols
  const int py  = lane >> 2;   // 16 rows
  const int xg4 = xg * 4;

  float acc[ON * 4];
#pragma unroll
  for (int i = 0; i < ON * 4; ++i) acc[i] = 0.f;

  for (int cb = 0; cb < NCB; ++cb) {
    __syncthreads();                       // barrier #1 (matched across waves)
    stage(qg, kg, t, cb, b, X0, Y0, tid);
    __syncthreads();                       // barrier #2
    for (int c = 0; c < NC; ++c) {
      float qa[4];
      *(float4*)qa = *(const float4*)&t.qs[c][py][xg4];
      float kr[3][12];                     // 3 di rows x 12-col span, all compile-time indexed
#pragma unroll
      for (int d = 0; d < 3; ++d) {
#pragma unroll
        for (int h = 0; h < 3; ++h)
          *(float4*)&kr[d][h * 4] = *(const float4*)&t.ks[c][py + DI0 + d][xg4 + h * 4];
      }
#pragma unroll
      for (int oi = 0; oi < ON; ++oi) {
        const int o  = OB + oi;
        const int di = o / 9 - DI0;
        const int dj = o % 9;
#pragma unroll
        for (int p = 0; p < 4; ++p)
          acc[oi * 4 + p] = __builtin_fmaf(qa[p], kr[di][dj + p], acc[oi * 4 + p]);
      }
    }
  }

  // Epilogue: per offset, cross-thread 3x3 box sum via per-wave LDS tile.
  // All waves run 21 iterations so barrier counts match.
#pragma unroll 1
  for (int it = 0; it < 21; ++it) {
    __syncthreads();
    if (it < ON) {
      // acc index is it*4 — 'it' is a runtime loop var, but the store below uses
      // contiguous float4, so force compile-time extraction via switch-free copy:
      float4 v;
      // it < ON <= 21; acc is register array — index with unrolled select
      float a0 = 0.f, a1 = 0.f, a2 = 0.f, a3 = 0.f;
#pragma unroll
      for (int q2 = 0; q2 < ON; ++q2) {
        if (q2 == it) { a0 = acc[q2*4]; a1 = acc[q2*4+1]; a2 = acc[q2*4+2]; a3 = acc[q2*4+3]; }
      }
      v = make_float4(a0, a1, a2, a3);
      *(float4*)&t.pt[w][py][xg4] = v;
    }
    __syncthreads();
    if (it < ON && py < OTILE) {
      float vsum[6];
#pragma unroll
      for (int j = 0; j < 6; ++j)
        vsum[j] = t.pt[w][py][xg4 + j] + t.pt[w][py + 1][xg4 + j] + t.pt[w][py + 2][xg4 + j];
      const int o  = OB + it;
      const int gy = Y0 + py;
      if (gy < IMG) {
        float* orow = out + ((size_t)(b * 81 + o) * IMG + gy) * IMG;
#pragma unroll
        for (int p = 0; p < 4; ++p) {
          const int xl = xg4 + p;
          const int gx = X0 + xl;
          if (xl < OTILE && gx < IMG)
            orow[gx] = vsum[p] + vsum[p + 1] + vsum[p + 2];
        }
      }
    }
  }
}

__global__ __launch_bounds__(256) void spatial_corr_kernel(const float* __restrict__ q,
                                                           const float* __restrict__ k,
                                                           float* __restrict__ out) {
  __shared__ Tiles t;
  const int tid  = threadIdx.x;
  const int w    = tid >> 6;
  const int lane = tid & 63;
  const int b  = blockIdx.z;
  const int X0 = blockIdx.x * OTILE;
  const int Y0 = blockIdx.y * OTILE;
  if (w == 0)      run<0,  21>(q, k, out, t, b, X0, Y0, tid, w, lane);
  else if (w == 1) run<21, 20>(q, k, out, t, b, X0, Y0, tid, w, lane);
  else if (w == 2) run<41, 20>(q, k, out, t, b, X0, Y0, tid, w, lane);
  else             run<61, 20>(q, k, out, t, b, X0, Y0, tid, w, lane);
}

extern "C" void kernel_launch(void* const* d_in, const int* in_sizes, int n_in,
                              void* d_out, int out_size, void* d_ws, size_t ws_size,
                              hipStream_t stream) {
  const float* q = (const float*)d_in[0];
  const float* k = (const float*)d_in[1];
  // d_in[2] (value) is unused by the reference output.
  float* out = (float*)d_out;
  dim3 grid(7, 7, BATCH);   // x-tiles, y-tiles, batch
  dim3 block(256);
  hipLaunchKernelGGL(spatial_corr_kernel, grid, block, 0, stream, q, k, out);
}

// Round 2
// 603.796 us; speedup vs baseline: 1.1019x; 1.1019x over previous
//
#include <hip/hip_runtime.h>

// Spatial correlation (cost volume), B=8 C=128 H=W=96, patch 9x9, 3x3 box, pad 1.
// out[b,di,dj,y,x] = sum_{i,j in 0..2} P[b,di,dj,y+i,x+j]
// P[b,di,dj,y',x'] = sum_c q_pad[y',x'] * k_pad[y'+di, x'+dj]   (padded 98x98 grid)
// q_pad[y'] = q[y'-1] (zero OOB), k_pad[a] = k[a-5] (zero OOB).
//
// R1: 2-way channel split (784 blocks, atomicAdd combine), conflict-free LDS
// strides (QTP=16, KTP=48: stride = 16 mod 32 words -> every 8 consecutive
// lanes of a ds_read_b128 cover all 32 banks exactly once), shuffle-based
// box-sum epilogue (no barriers, no LDS round-trip).

#define BATCH 8
#define CHN   128
#define IMG   96
#define TILE  16    // P-tile edge (padded-grid points) per block
#define OTILE 14    // output-tile edge per block (TILE - 2)
#define NC    8     // channels staged per pass
#define CHALF 64    // channels per block (2-way split)
#define NCB   (CHALF / NC)
#define KT    24    // k-tile edge (TILE + 8)
#define KTP   48    // k-tile col stride: 48 % 32 == 16 -> conflict-free b128
#define QTP   16    // q-tile col stride: 16 -> conflict-free b128

struct Tiles {
  float qs[NC][TILE][QTP];   //  8192 B (flat-linear staging writes)
  float ks[NC][KT][KTP];     // 36864 B (cols 24..47 unused padding)
};                           // 45056 B total -> 3 blocks/CU

__device__ inline void stage(const float* __restrict__ qg, const float* __restrict__ kg,
                             Tiles& t, int cbase, int b, int X0, int Y0, int tid) {
  // q tile: NC*16*16 = 2048 elems; LDS layout is flat-linear in idx.
  float* qflat = &t.qs[0][0][0];
  for (int idx = tid; idx < NC * TILE * TILE; idx += 256) {
    const int c = idx >> 8;
    const int rem = idx & 255;
    const int r = rem >> 4, col = rem & 15;
    const int gy = Y0 + r - 1, gx = X0 + col - 1;
    float v = 0.f;
    if ((unsigned)gy < IMG && (unsigned)gx < IMG)
      v = qg[((size_t)(b * CHN + cbase + c) * IMG + gy) * IMG + gx];
    qflat[idx] = v;
  }
  // k tile: NC*24*24 = 4608 elems
  for (int idx = tid; idx < NC * KT * KT; idx += 256) {
    const int c = idx / (KT * KT);
    const int rem = idx - c * (KT * KT);
    const int r = rem / KT, col = rem - r * KT;
    const int gy = Y0 + r - 5, gx = X0 + col - 5;
    float v = 0.f;
    if ((unsigned)gy < IMG && (unsigned)gx < IMG)
      v = kg[((size_t)(b * CHN + cbase + c) * IMG + gy) * IMG + gx];
    t.ks[c][r][col] = v;
  }
}

__device__ constexpr int di_lo_o(int OB, int d) {  // first offset of row d in this wave
  const int di = OB / 9 + d;
  return OB > di * 9 ? OB : di * 9;
}
__device__ constexpr int di_hi_o(int OB, int ON, int d) {  // one-past-last
  const int di = OB / 9 + d;
  return (OB + ON) < (di * 9 + 9) ? (OB + ON) : (di * 9 + 9);
}
__device__ constexpr bool h_needed(int OB, int ON, int d, int h) {
  const int lo = di_lo_o(OB, d), hi = di_hi_o(OB, ON, d);
  if (lo >= hi) return false;
  const int di = OB / 9 + d;
  const int clo = lo - di * 9, chi = (hi - 1 - di * 9) + 3;  // col span used
  return (4 * h <= chi) && (4 * h + 3 >= clo);
}

template <int OB, int ON, int d>
__device__ inline void do_row(const Tiles& t, int c, int py, int xg4,
                              const float (&qa)[4], float (&acc)[ON * 4]) {
  if constexpr (di_lo_o(OB, d) < di_hi_o(OB, ON, d)) {
    constexpr int DI0 = OB / 9;
    float kd[12];
    if constexpr (h_needed(OB, ON, d, 0)) *(float4*)&kd[0] = *(const float4*)&t.ks[c][py + DI0 + d][xg4 + 0];
    if constexpr (h_needed(OB, ON, d, 1)) *(float4*)&kd[4] = *(const float4*)&t.ks[c][py + DI0 + d][xg4 + 4];
    if constexpr (h_needed(OB, ON, d, 2)) *(float4*)&kd[8] = *(const float4*)&t.ks[c][py + DI0 + d][xg4 + 8];
#pragma unroll
    for (int oi = 0; oi < ON; ++oi) {
      if ((OB + oi) / 9 == DI0 + d) {            // constant-folded after unroll
        const int dj = (OB + oi) - ((OB + oi) / 9) * 9;
#pragma unroll
        for (int p = 0; p < 4; ++p)
          acc[oi * 4 + p] = __builtin_fmaf(qa[p], kd[dj + p], acc[oi * 4 + p]);
      }
    }
  }
}

template <int OB, int ON>
__device__ void run(const float* __restrict__ qg, const float* __restrict__ kg,
                    float* __restrict__ out, Tiles& t,
                    int b, int cbase0, int X0, int Y0, int tid, int lane) {
  const int xg  = lane & 3;    // 4 x-groups of 4 points = 16 cols
  const int py  = lane >> 2;   // 16 rows
  const int xg4 = xg * 4;

  float acc[ON * 4];
#pragma unroll
  for (int i = 0; i < ON * 4; ++i) acc[i] = 0.f;

  for (int cb = 0; cb < NCB; ++cb) {
    __syncthreads();                       // barrier #1 (matched across waves)
    stage(qg, kg, t, cbase0 + cb * NC, b, X0, Y0, tid);
    __syncthreads();                       // barrier #2
#pragma unroll 2
    for (int c = 0; c < NC; ++c) {
      float qa[4];
      *(float4*)qa = *(const float4*)&t.qs[c][py][xg4];
      do_row<OB, ON, 0>(t, c, py, xg4, qa, acc);
      do_row<OB, ON, 1>(t, c, py, xg4, qa, acc);
      do_row<OB, ON, 2>(t, c, py, xg4, qa, acc);
    }
  }

  // Epilogue: 3x3 box sum entirely with shuffles (no LDS, no barriers).
  // x-dir: lane holds P at cols xg4..xg4+3; cols xg4+4, xg4+5 come from lane+1.
  const int srcx = (xg < 3) ? (lane + 1) : lane;   // xg==3 values unused
  const int gy   = Y0 + py;
  const bool rowok = (py < OTILE) && (gy < IMG);
  float* obase = out + ((size_t)b * 81 * IMG + gy) * IMG + X0;  // + o*IMG*IMG later
#pragma unroll
  for (int oi = 0; oi < ON; ++oi) {
    const float a0 = acc[oi * 4 + 0], a1 = acc[oi * 4 + 1];
    const float a2 = acc[oi * 4 + 2], a3 = acc[oi * 4 + 3];
    const float a0n = __shfl(a0, srcx);
    const float a1n = __shfl(a1, srcx);
    float s0 = a0 + a1 + a2;
    float s1 = a1 + a2 + a3;
    float s2 = a2 + a3 + a0n;
    float s3 = a3 + a0n + a1n;
    // y-dir: rows py, py+1, py+2 live in lanes +4, +8
    s0 += __shfl_down(s0, 4) + __shfl_down(s0, 8);
    s1 += __shfl_down(s1, 4) + __shfl_down(s1, 8);
    s2 += __shfl_down(s2, 4) + __shfl_down(s2, 8);
    s3 += __shfl_down(s3, 4) + __shfl_down(s3, 8);
    if (rowok) {
      const int o = OB + oi;
      float* orow = obase + (size_t)o * IMG * IMG;
      if (xg4 + 0 < OTILE && X0 + xg4 + 0 < IMG) atomicAdd(&orow[xg4 + 0], s0);
      if (xg4 + 1 < OTILE && X0 + xg4 + 1 < IMG) atomicAdd(&orow[xg4 + 1], s1);
      if (xg4 + 2 < OTILE && X0 + xg4 + 2 < IMG) atomicAdd(&orow[xg4 + 2], s2);
      if (xg4 + 3 < OTILE && X0 + xg4 + 3 < IMG) atomicAdd(&orow[xg4 + 3], s3);
    }
  }
}

__global__ __launch_bounds__(256, 3) void spatial_corr_kernel(const float* __restrict__ q,
                                                              const float* __restrict__ k,
                                                              float* __restrict__ out) {
  __shared__ Tiles t;
  const int tid  = threadIdx.x;
  const int w    = tid >> 6;
  const int lane = tid & 63;
  const int b      = blockIdx.z >> 1;
  const int cbase0 = (blockIdx.z & 1) * CHALF;
  const int X0 = blockIdx.x * OTILE;
  const int Y0 = blockIdx.y * OTILE;
  if (w == 0)      run<0,  21>(q, k, out, t, b, cbase0, X0, Y0, tid, lane);
  else if (w == 1) run<21, 20>(q, k, out, t, b, cbase0, X0, Y0, tid, lane);
  else if (w == 2) run<41, 20>(q, k, out, t, b, cbase0, X0, Y0, tid, lane);
  else             run<61, 20>(q, k, out, t, b, cbase0, X0, Y0, tid, lane);
}

extern "C" void kernel_launch(void* const* d_in, const int* in_sizes, int n_in,
                              void* d_out, int out_size, void* d_ws, size_t ws_size,
                              hipStream_t stream) {
  const float* q = (const float*)d_in[0];
  const float* k = (const float*)d_in[1];
  // d_in[2] (value) is unused by the reference output.
  float* out = (float*)d_out;
  hipMemsetAsync(out, 0, (size_t)out_size * sizeof(float), stream);
  dim3 grid(7, 7, BATCH * 2);   // x-tiles, y-tiles, batch x channel-half
  dim3 block(256);
  hipLaunchKernelGGL(spatial_corr_kernel, grid, block, 0, stream, q, k, out);
}

// Round 3
// 533.194 us; speedup vs baseline: 1.2478x; 1.1324x over previous
//
#include <hip/hip_runtime.h>

// Spatial correlation (cost volume), B=8 C=128 H=W=96, patch 9x9, 3x3 box, pad 1.
// out[b,di,dj,y,x] = sum_{i,j in 0..2} P[b,di,dj,y+i,x+j]
// P[b,di,dj,y',x'] = sum_c q_pad[y',x'] * k_pad[y'+di, x'+dj]   (padded 98x98 grid)
//
// R2: fix the R1 killer — acc[84] spilled to scratch (VGPR=68 < live set),
// making the kernel L2-BW-bound on spill traffic (17GB/504us = 34 TB/s = L2
// ceiling). Now 8 waves/block, <=44 acc/thread, launch_bounds(512,1) so the
// accumulators stay in VGPRs. Each wave's offset window spans only 2 di rows.

#define BATCH 8
#define CHN   128
#define IMG   96
#define TILE  16    // P-tile edge (padded-grid points) per block
#define OTILE 14    // output-tile edge per block (TILE - 2)
#define NC    8     // channels staged per pass
#define CHALF 64    // channels per block (2-way split)
#define NCB   (CHALF / NC)
#define KT    24    // k-tile edge (TILE + 8)
#define KTP   48    // k-tile col stride: 48 % 32 == 16 -> conflict-free b128
#define QTP   16    // q-tile col stride
#define NTHR  512

struct Tiles {
  float qs[NC][TILE][QTP];   //  8192 B (flat-linear staging writes)
  float ks[NC][KT][KTP];     // 36864 B (cols 24..47 unused padding)
};                           // 45056 B total

__device__ inline void stage(const float* __restrict__ qg, const float* __restrict__ kg,
                             Tiles& t, int cbase, int b, int X0, int Y0, int tid) {
  float* qflat = &t.qs[0][0][0];
  for (int idx = tid; idx < NC * TILE * TILE; idx += NTHR) {
    const int c = idx >> 8;
    const int rem = idx & 255;
    const int r = rem >> 4, col = rem & 15;
    const int gy = Y0 + r - 1, gx = X0 + col - 1;
    float v = 0.f;
    if ((unsigned)gy < IMG && (unsigned)gx < IMG)
      v = qg[((size_t)(b * CHN + cbase + c) * IMG + gy) * IMG + gx];
    qflat[idx] = v;
  }
  for (int idx = tid; idx < NC * KT * KT; idx += NTHR) {
    const int c = idx / (KT * KT);
    const int rem = idx - c * (KT * KT);
    const int r = rem / KT, col = rem - r * KT;
    const int gy = Y0 + r - 5, gx = X0 + col - 5;
    float v = 0.f;
    if ((unsigned)gy < IMG && (unsigned)gx < IMG)
      v = kg[((size_t)(b * CHN + cbase + c) * IMG + gy) * IMG + gx];
    t.ks[c][r][col] = v;
  }
}

__device__ constexpr int di_lo_o(int OB, int d) {
  const int di = OB / 9 + d;
  return OB > di * 9 ? OB : di * 9;
}
__device__ constexpr int di_hi_o(int OB, int ON, int d) {
  const int di = OB / 9 + d;
  return (OB + ON) < (di * 9 + 9) ? (OB + ON) : (di * 9 + 9);
}
__device__ constexpr bool h_needed(int OB, int ON, int d, int h) {
  const int lo = di_lo_o(OB, d), hi = di_hi_o(OB, ON, d);
  if (lo >= hi) return false;
  const int di = OB / 9 + d;
  const int clo = lo - di * 9, chi = (hi - 1 - di * 9) + 3;
  return (4 * h <= chi) && (4 * h + 3 >= clo);
}

template <int OB, int ON, int d>
__device__ inline void do_row(const Tiles& t, int c, int py, int xg4,
                              const float (&qa)[4], float (&acc)[ON * 4]) {
  if constexpr (di_lo_o(OB, d) < di_hi_o(OB, ON, d)) {
    constexpr int DI0 = OB / 9;
    float kd[12];
    if constexpr (h_needed(OB, ON, d, 0)) *(float4*)&kd[0] = *(const float4*)&t.ks[c][py + DI0 + d][xg4 + 0];
    if constexpr (h_needed(OB, ON, d, 1)) *(float4*)&kd[4] = *(const float4*)&t.ks[c][py + DI0 + d][xg4 + 4];
    if constexpr (h_needed(OB, ON, d, 2)) *(float4*)&kd[8] = *(const float4*)&t.ks[c][py + DI0 + d][xg4 + 8];
#pragma unroll
    for (int oi = 0; oi < ON; ++oi) {
      if ((OB + oi) / 9 == DI0 + d) {            // constant-folded after unroll
        const int dj = (OB + oi) - ((OB + oi) / 9) * 9;
#pragma unroll
        for (int p = 0; p < 4; ++p)
          acc[oi * 4 + p] = __builtin_fmaf(qa[p], kd[dj + p], acc[oi * 4 + p]);
      }
    }
  }
}

template <int OB, int ON>
__device__ void run(const float* __restrict__ qg, const float* __restrict__ kg,
                    float* __restrict__ out, Tiles& t,
                    int b, int cbase0, int X0, int Y0, int tid, int lane) {
  const int xg  = lane & 3;    // 4 x-groups of 4 points = 16 cols
  const int py  = lane >> 2;   // 16 rows
  const int xg4 = xg * 4;

  float acc[ON * 4];
#pragma unroll
  for (int i = 0; i < ON * 4; ++i) acc[i] = 0.f;

  for (int cb = 0; cb < NCB; ++cb) {
    __syncthreads();                       // barrier #1 (matched across waves)
    stage(qg, kg, t, cbase0 + cb * NC, b, X0, Y0, tid);
    __syncthreads();                       // barrier #2
#pragma unroll 2
    for (int c = 0; c < NC; ++c) {
      float qa[4];
      *(float4*)qa = *(const float4*)&t.qs[c][py][xg4];
      do_row<OB, ON, 0>(t, c, py, xg4, qa, acc);
      do_row<OB, ON, 1>(t, c, py, xg4, qa, acc);
      do_row<OB, ON, 2>(t, c, py, xg4, qa, acc);
    }
  }

  // Epilogue: 3x3 box sum entirely with shuffles (no LDS, no barriers).
  const int srcx = (xg < 3) ? (lane + 1) : lane;   // xg==3 values unused
  const int gy   = Y0 + py;
  const bool rowok = (py < OTILE) && (gy < IMG);
  float* obase = out + ((size_t)b * 81 * IMG + gy) * IMG + X0;
#pragma unroll
  for (int oi = 0; oi < ON; ++oi) {
    const float a0 = acc[oi * 4 + 0], a1 = acc[oi * 4 + 1];
    const float a2 = acc[oi * 4 + 2], a3 = acc[oi * 4 + 3];
    const float a0n = __shfl(a0, srcx);
    const float a1n = __shfl(a1, srcx);
    float s0 = a0 + a1 + a2;
    float s1 = a1 + a2 + a3;
    float s2 = a2 + a3 + a0n;
    float s3 = a3 + a0n + a1n;
    s0 += __shfl_down(s0, 4) + __shfl_down(s0, 8);
    s1 += __shfl_down(s1, 4) + __shfl_down(s1, 8);
    s2 += __shfl_down(s2, 4) + __shfl_down(s2, 8);
    s3 += __shfl_down(s3, 4) + __shfl_down(s3, 8);
    if (rowok) {
      const int o = OB + oi;
      float* orow = obase + (size_t)o * IMG * IMG;
      if (xg4 + 0 < OTILE && X0 + xg4 + 0 < IMG) atomicAdd(&orow[xg4 + 0], s0);
      if (xg4 + 1 < OTILE && X0 + xg4 + 1 < IMG) atomicAdd(&orow[xg4 + 1], s1);
      if (xg4 + 2 < OTILE && X0 + xg4 + 2 < IMG) atomicAdd(&orow[xg4 + 2], s2);
      if (xg4 + 3 < OTILE && X0 + xg4 + 3 < IMG) atomicAdd(&orow[xg4 + 3], s3);
    }
  }
}

__global__ __launch_bounds__(NTHR, 1) void spatial_corr_kernel(const float* __restrict__ q,
                                                               const float* __restrict__ k,
                                                               float* __restrict__ out) {
  __shared__ Tiles t;
  const int tid  = threadIdx.x;
  const int w    = tid >> 6;
  const int lane = tid & 63;
  const int b      = blockIdx.z >> 1;
  const int cbase0 = (blockIdx.z & 1) * CHALF;
  const int X0 = blockIdx.x * OTILE;
  const int Y0 = blockIdx.y * OTILE;
  // 8 waves x (11,10,...,10) offsets; every window spans exactly 2 di rows.
  if (w == 0)      run<0,  11>(q, k, out, t, b, cbase0, X0, Y0, tid, lane);
  else if (w == 1) run<11, 10>(q, k, out, t, b, cbase0, X0, Y0, tid, lane);
  else if (w == 2) run<21, 10>(q, k, out, t, b, cbase0, X0, Y0, tid, lane);
  else if (w == 3) run<31, 10>(q, k, out, t, b, cbase0, X0, Y0, tid, lane);
  else if (w == 4) run<41, 10>(q, k, out, t, b, cbase0, X0, Y0, tid, lane);
  else if (w == 5) run<51, 10>(q, k, out, t, b, cbase0, X0, Y0, tid, lane);
  else if (w == 6) run<61, 10>(q, k, out, t, b, cbase0, X0, Y0, tid, lane);
  else             run<71, 10>(q, k, out, t, b, cbase0, X0, Y0, tid, lane);
}

extern "C" void kernel_launch(void* const* d_in, const int* in_sizes, int n_in,
                              void* d_out, int out_size, void* d_ws, size_t ws_size,
                              hipStream_t stream) {
  const float* q = (const float*)d_in[0];
  const float* k = (const float*)d_in[1];
  // d_in[2] (value) is unused by the reference output.
  float* out = (float*)d_out;
  hipMemsetAsync(out, 0, (size_t)out_size * sizeof(float), stream);
  dim3 grid(7, 7, BATCH * 2);   // x-tiles, y-tiles, batch x channel-half
  dim3 block(NTHR);
  hipLaunchKernelGGL(spatial_corr_kernel, grid, block, 0, stream, q, k, out);
}